// Round 2
// baseline (634.367 us; speedup 1.0000x reference)
//
#include <hip/hip_runtime.h>
#include <hip/hip_cooperative_groups.h>

namespace cg = cooperative_groups;

// BatchIndependentLoss: SupCon-style loss, B=2048, V=2, D=256, N=4096.
// loss = -mean_i( lp_i - (W_i - e^{lp}*lp) / u_new[i%B] )
// R10: dispatch-structure attack. R9 (halved exp2, +occupancy) moved only
// -1.9 us => gemm internals were never the governing term. Arithmetic says
// our 3 kernels sum to ~20-40 us while dur_us=114 with a fixed ~41 us
// harness fill inside the window => the rest is inter-dispatch boundaries.
// Fuse prep+gemm+finalize into ONE cooperative kernel (2080 blocks x 64),
// two grid.sync()s replace two kernel boundaries; finalize parallelized
// across 64 blocks (was 1 block) with atomicAdd into out.
//  - phase A: zero S1/S2/out + frag-major bf16 pack
//  - phase B: barrier-free symmetric GEMM, unshifted exp2 domain
//             (f = exp2(d*C1); S1 += f; S2 += f*d*C1; per-row 2^msd shift
//             applied in phase C; msd recovered from diagonal tiles)
//  - phase C: per-row unew recompute + loss reduction, 64 blocks
// Runtime fallback to the 3-kernel path if cooperative launch is refused.
//
// CmF layout: shorts, index = ((band*8 + k)*4 + rt)*512 + (l15*4+quad)*8 + j
// Fragment load for (band, k, rt): wave reads one contiguous 1 KB chunk.

#define BSZ   2048
#define NROW  4096
#define DDIM  256
#define NB64  64                       // 4096/64 bands
#define NT2   (NB64 * (NB64 + 1) / 2)  // 2080 upper-triangle 64x64 tiles
#define GSZ   (NT2 * 64)               // 133120 threads
#define C1    (1.4426950408889634f / 0.07f)   // log2(e)/TEMPERATURE
#define LN2   0.6931471805599453f

typedef __attribute__((ext_vector_type(8))) __bf16 bf16x8;
typedef __attribute__((ext_vector_type(4))) float f32x4;

__device__ __forceinline__ short f2bs(float x) {
    __bf16 b = (__bf16)x;
    return __builtin_bit_cast(short, b);
}

// contrast row i = v*B + b  ->  features row b*V + v  (fp32, 256 elems)
__device__ __forceinline__ const float* crow_ptr(const float* feats, int i) {
    return feats + (((i & (BSZ - 1)) * 2 + (i >> 11)) << 8);
}

// ---- pack one gid unit (8 shorts) of the frag-major bf16 operand ----------
__device__ __forceinline__ void pack_unit(const float* __restrict__ feats,
                                          short* __restrict__ CmF, int gid) {
    int quad = gid & 3;
    int l15  = (gid >> 2) & 15;
    int rt   = (gid >> 6) & 3;
    int k    = (gid >> 8) & 7;
    int b    = gid >> 12;
    int srow = (b << 6) + (rt << 4) + l15;
    int kel  = (k << 5) + (quad << 3);
    const float4* fp = (const float4*)(crow_ptr(feats, srow) + kel);
    float4 v0 = fp[0], v1 = fp[1];
    short h[8] = { f2bs(v0.x), f2bs(v0.y), f2bs(v0.z), f2bs(v0.w),
                   f2bs(v1.x), f2bs(v1.y), f2bs(v1.z), f2bs(v1.w) };
    *(int4*)(CmF + gid * 8) = *(int4*)h;
}

// ---- gemm tile body: one wave = one 64x64 upper-tri tile ------------------
__device__ __forceinline__ void gemm_tile(const short* __restrict__ CmF,
        float* __restrict__ S1, float* __restrict__ S2,
        float* __restrict__ Praw, float* __restrict__ Draw,
        int t, int lane) {
    int quad = lane >> 4;
    int l15  = lane & 15;

    // triangle decode t -> (p,q), p>=q
    int p = (int)((sqrtf(8.0f * (float)t + 1.0f) - 1.0f) * 0.5f);
    while ((p + 1) * (p + 2) / 2 <= t) ++p;
    while (p * (p + 1) / 2 > t) --p;
    int q = t - p * (p + 1) / 2;
    int rowBase = q << 6;            // row band (64)
    int colBase = p << 6;            // col band, >= row band
    bool offdiag = (p != q);

    int laneOff = ((l15 << 2) + quad) * 8;
    int aO = q * 16384 + laneOff;
    int bO = p * 16384 + laneOff;

    f32x4 acc[4][4];
    #pragma unroll
    for (int a = 0; a < 4; ++a)
        #pragma unroll
        for (int c = 0; c < 4; ++c) acc[a][c] = (f32x4){0.f, 0.f, 0.f, 0.f};

    // depth-1 software pipeline: 2 rotating fragment buffers
    bf16x8 aF[2][4], bF[2][4];
    #pragma unroll
    for (int rt = 0; rt < 4; ++rt) {
        aF[0][rt] = *(const bf16x8*)(CmF + aO + rt * 512);
        bF[0][rt] = *(const bf16x8*)(CmF + bO + rt * 512);
    }

    #pragma unroll
    for (int k = 0; k < 8; ++k) {
        int cur = k & 1;
        int nxt = cur ^ 1;
        if (k < 7) {                 // issue loads for step k+1
            #pragma unroll
            for (int rt = 0; rt < 4; ++rt) {
                aF[nxt][rt] = *(const bf16x8*)(CmF + aO + ((k + 1) * 4 + rt) * 512);
                bF[nxt][rt] = *(const bf16x8*)(CmF + bO + ((k + 1) * 4 + rt) * 512);
            }
        }
        __builtin_amdgcn_s_setprio(1);
        #pragma unroll
        for (int rt = 0; rt < 4; ++rt)
            #pragma unroll
            for (int ct = 0; ct < 4; ++ct)
                acc[rt][ct] = __builtin_amdgcn_mfma_f32_16x16x32_bf16(
                    aF[cur][rt], bF[cur][ct], acc[rt][ct], 0, 0, 0);
        __builtin_amdgcn_s_setprio(0);
    }

    // ---- epilogue: C/D layout col = lane&15, row = quad*4 + reg  [m89/m91]
    // Unshifted domain: one exp2 per element, feeds BOTH row and col sums.
    float S1r[4][4] = {}, S2r[4][4] = {};
    float S1c[4] = {}, S2c[4] = {};
    #pragma unroll
    for (int rt = 0; rt < 4; ++rt) {
        #pragma unroll
        for (int ct = 0; ct < 4; ++ct) {
            #pragma unroll
            for (int r = 0; r < 4; ++r) {
                float d  = acc[rt][ct][r];
                float t0 = d * C1;
                float f  = __builtin_exp2f(t0);
                S1r[rt][r] += f;
                S2r[rt][r] = __builtin_fmaf(f, t0, S2r[rt][r]);
                if (offdiag) {
                    S1c[ct] += f;
                    S2c[ct] = __builtin_fmaf(f, t0, S2c[ct]);
                }
            }
        }
    }

    // ---- Praw: only tiles with p == q^32 contain positives (j = i^2048)
    if (p == (q ^ 32)) {
        if (quad == (l15 >> 2)) {
            int r = l15 & 3;
            #pragma unroll
            for (int rt = 0; rt < 4; ++rt) {
                float t0 = acc[rt][rt][r] * C1;
                Praw[rowBase + rt * 16 + l15] = t0;
                Praw[colBase + rt * 16 + l15] = t0;
            }
        }
    }
    // ---- Draw: diagonal tiles hold the self-dot (msd = -Draw in phase C)
    if (!offdiag) {
        if (quad == (l15 >> 2)) {
            int r = l15 & 3;
            #pragma unroll
            for (int rt = 0; rt < 4; ++rt)
                Draw[rowBase + rt * 16 + l15] = acc[rt][rt][r] * C1;
        }
    }

    // row-path: reduce over 16 l15 lanes per row, 1-lane atomic per row
    #pragma unroll
    for (int rt = 0; rt < 4; ++rt) {
        #pragma unroll
        for (int r = 0; r < 4; ++r) {
            float e = S1r[rt][r], w = S2r[rt][r];
            #pragma unroll
            for (int off = 1; off < 16; off <<= 1) {
                e += __shfl_xor(e, off, 64);
                w += __shfl_xor(w, off, 64);
            }
            if (l15 == 0) {
                int grow = rowBase + rt * 16 + (quad << 2) + r;
                atomicAdd(&S1[grow], e);
                atomicAdd(&S2[grow], w);
            }
        }
    }
    // col-path: reduce over 4 quads per col, 16-lane atomic
    if (offdiag) {
        #pragma unroll
        for (int ct = 0; ct < 4; ++ct) {
            float e = S1c[ct], w = S2c[ct];
            e += __shfl_xor(e, 16, 64);  w += __shfl_xor(w, 16, 64);
            e += __shfl_xor(e, 32, 64);  w += __shfl_xor(w, 32, 64);
            if (quad == 0) {
                int gcol = colBase + ct * 16 + l15;
                atomicAdd(&S1[gcol], e);
                atomicAdd(&S2[gcol], w);
            }
        }
    }
}

// ---------------- fused cooperative kernel ---------------------------------
__global__ __launch_bounds__(64, 3) void fused_all(
        const int* __restrict__ index, const float* __restrict__ feats,
        const float* __restrict__ u, float* __restrict__ S1,
        float* __restrict__ S2, float* __restrict__ Praw,
        float* __restrict__ Draw, short* __restrict__ CmF,
        float* __restrict__ out) {
    cg::grid_group grid = cg::this_grid();
    int lane = threadIdx.x;
    int bid  = blockIdx.x;
    int tid0 = (bid << 6) + lane;

    // ---- phase A: zero S1/S2 (contiguous 8192 floats) + out, bf16 pack ----
    if (tid0 < 2 * NROW) S1[tid0] = 0.0f;
    if (tid0 == 0) out[0] = 0.0f;
    for (int gid = tid0; gid < 262144; gid += GSZ)
        pack_unit(feats, CmF, gid);

    __threadfence();
    grid.sync();

    // ---- phase B: symmetric GEMM + row/col stats ----
    gemm_tile(CmF, S1, S2, Praw, Draw, bid, lane);

    __threadfence();
    grid.sync();

    // ---- phase C: per-row unew + loss reduction (64 blocks x 64 rows) ----
    if (bid < NROW / 64) {
        int i = tid0;                    // 0..4095
        int b = i & (BSZ - 1);
        // unew for this row's batch element (recomputed per row; cheap)
        float mb  = -Draw[b];
        float tpb = Praw[b] + mb;
        float Eb  = __builtin_exp2f(mb) * S1[b];
        float unew = 0.1f * u[index[b]] + 0.9f * (Eb - __builtin_exp2f(tpb));
        // this row's loss term
        float m   = -Draw[i];
        float tp  = Praw[i] + m;
        float etp = __builtin_exp2f(tp);
        float W   = __builtin_exp2f(m) * __builtin_fmaf(m, S1[i], S2[i]);
        float local = tp - (W - etp * tp) / unew;
        #pragma unroll
        for (int off = 32; off; off >>= 1) local += __shfl_xor(local, off, 64);
        if (lane == 0) atomicAdd(out, -LN2 * local / (float)NROW);
    }
}

// ---------------- fallback 3-kernel path (R9) ------------------------------
__global__ __launch_bounds__(256) void prep_kernel(const float* __restrict__ feats,
        float* __restrict__ Szero, short* __restrict__ CmF) {
    int gid = blockIdx.x * 256 + threadIdx.x;    // 0..262143
    if (gid < 2 * NROW) Szero[gid] = 0.0f;
    pack_unit(feats, CmF, gid);
}

__global__ __launch_bounds__(64, 3) void gemm_sym(const short* __restrict__ CmF,
        float* __restrict__ S1, float* __restrict__ S2,
        float* __restrict__ Praw, float* __restrict__ Draw) {
    gemm_tile(CmF, S1, S2, Praw, Draw, blockIdx.x, threadIdx.x);
}

__global__ __launch_bounds__(1024) void finalize_kernel(const int* __restrict__ index,
        const float* __restrict__ u, const float* __restrict__ S1,
        const float* __restrict__ S2, const float* __restrict__ Praw,
        const float* __restrict__ Draw, float* __restrict__ out) {
    __shared__ float unew[BSZ];
    __shared__ float partial[16];
    int tid = threadIdx.x;
    for (int b = tid; b < BSZ; b += 1024) {
        float m  = -Draw[b];
        float tp = Praw[b] + m;
        float E  = __builtin_exp2f(m) * S1[b];
        unew[b] = 0.1f * u[index[b]] + 0.9f * (E - __builtin_exp2f(tp));
    }
    __syncthreads();
    float local = 0.0f;
    for (int i = tid; i < NROW; i += 1024) {
        float m   = -Draw[i];
        float tp  = Praw[i] + m;
        float etp = __builtin_exp2f(tp);
        float W   = __builtin_exp2f(m) * __builtin_fmaf(m, S1[i], S2[i]);
        local += tp - (W - etp * tp) / unew[i & (BSZ - 1)];
    }
    #pragma unroll
    for (int off = 32; off; off >>= 1) local += __shfl_xor(local, off, 64);
    if ((tid & 63) == 0) partial[tid >> 6] = local;
    __syncthreads();
    if (tid == 0) {
        float s = 0.0f;
        #pragma unroll
        for (int w = 0; w < 16; ++w) s += partial[w];
        out[0] = -LN2 * s / (float)NROW;
    }
}

extern "C" void kernel_launch(void* const* d_in, const int* in_sizes, int n_in,
                              void* d_out, int out_size, void* d_ws, size_t ws_size,
                              hipStream_t stream) {
    const int*   index = (const int*)d_in[0];
    const float* feats = (const float*)d_in[1];
    const float* u     = (const float*)d_in[2];
    float* out = (float*)d_out;

    // ws: [S1|S2|Praw|Draw] (4x4096 f32 = 64 KB) | ... | CmF @128KB (2 MB)
    float* S1   = (float*)d_ws;
    float* S2   = S1 + NROW;
    float* Praw = S2 + NROW;
    float* Draw = Praw + NROW;
    short* CmF  = (short*)((char*)d_ws + 131072);

    void* args[] = { (void*)&index, (void*)&feats, (void*)&u,
                     (void*)&S1, (void*)&S2, (void*)&Praw, (void*)&Draw,
                     (void*)&CmF, (void*)&out };
    hipError_t e = hipLaunchCooperativeKernel((const void*)fused_all,
                                              dim3(NT2), dim3(64), args, 0, stream);
    if (e != hipSuccess) {
        // fallback: 3-kernel path (identical math)
        prep_kernel<<<1024, 256, 0, stream>>>(feats, S1, CmF);
        gemm_sym<<<NT2, 64, 0, stream>>>(CmF, S1, S2, Praw, Draw);
        finalize_kernel<<<1, 1024, 0, stream>>>(index, u, S1, S2, Praw, Draw, out);
    }
}

// Round 3
// 428.049 us; speedup vs baseline: 1.4820x; 1.4820x over previous
//
#include <hip/hip_runtime.h>

// BatchIndependentLoss: SupCon-style loss, B=2048, V=2, D=256, N=4096.
// loss = -mean_i( lp_i - (W_i - e^{lp}*lp) / u_new[i%B] )
// R11: boundary + occupancy attack (R10 lesson: cg::grid.sync = ~250us/sync
// on gfx950 at 2080 blocks -> never again; use atomic-causality fusion).
//  (a) finalize folded into gemm via per-band-pair completion counters:
//      pair {b, b+32} (b<32) is touched by exactly 127 tiles = 254
//      half-tile blocks. Each block __threadfence()s then agent-scope
//      fetch_adds its pairs' counters; the old==253 observer owns that
//      pair's finalize (64 unew + 128 loss rows on one wave, agent-scope
//      acquire loads, atomicAdd to out). No dispatch-order / co-residency
//      assumption. Deletes the finalize dispatch + boundary drain and
//      hides finalize latency under the gemm tail.
//  (b) row-split tiles: each 64x64 tile -> two 64-col x 32-row halves,
//      4160 single-wave blocks (16/CU, 4 waves/SIMD vs 2). Per-wave work
//      halves; chip-wide epilogue shuffle/atomic work ~constant (row-path
//      scales with rows owned). __launch_bounds__(64,4) caps VGPR at 128
//      so 4 waves/SIMD is allocatable (acc 64->32 regs).
// Math identical to R9 (unshifted exp2 domain: f=exp2(d*C1), S1+=f,
// S2+=f*d*C1; per-row 2^msd shift in finalize; msd from diagonal tiles).
//
// CmF layout: shorts, index = ((band*8 + k)*4 + rt)*512 + (l15*4+quad)*8 + j
// Fragment load for (band, k, rt): wave reads one contiguous 1 KB chunk.

#define BSZ   2048
#define NROW  4096
#define NB64  64                       // 4096/64 bands
#define NT2   (NB64 * (NB64 + 1) / 2)  // 2080 upper-triangle 64x64 tiles
#define NBLK  (NT2 * 2)                // 4160 half-tile blocks
#define PAIR_TGT 254                   // 127 tiles * 2 halves per band-pair
#define C1    (1.4426950408889634f / 0.07f)   // log2(e)/TEMPERATURE
#define LN2   0.6931471805599453f

typedef __attribute__((ext_vector_type(8))) __bf16 bf16x8;
typedef __attribute__((ext_vector_type(4))) float f32x4;

__device__ __forceinline__ short f2bs(float x) {
    __bf16 b = (__bf16)x;
    return __builtin_bit_cast(short, b);
}

// contrast row i = v*B + b  ->  features row b*V + v  (fp32, 256 elems)
__device__ __forceinline__ const float* crow_ptr(const float* feats, int i) {
    return feats + (((i & (BSZ - 1)) * 2 + (i >> 11)) << 8);
}

// ---- pack one gid unit (8 shorts) of the frag-major bf16 operand ----------
__device__ __forceinline__ void pack_unit(const float* __restrict__ feats,
                                          short* __restrict__ CmF, int gid) {
    int quad = gid & 3;
    int l15  = (gid >> 2) & 15;
    int rt   = (gid >> 6) & 3;
    int k    = (gid >> 8) & 7;
    int b    = gid >> 12;
    int srow = (b << 6) + (rt << 4) + l15;
    int kel  = (k << 5) + (quad << 3);
    const float4* fp = (const float4*)(crow_ptr(feats, srow) + kel);
    float4 v0 = fp[0], v1 = fp[1];
    short h[8] = { f2bs(v0.x), f2bs(v0.y), f2bs(v0.z), f2bs(v0.w),
                   f2bs(v1.x), f2bs(v1.y), f2bs(v1.z), f2bs(v1.w) };
    *(int4*)(CmF + gid * 8) = *(int4*)h;
}

// ---------------- prep: pack + zero S1/S2/counters/out ---------------------
__global__ __launch_bounds__(256) void prep_kernel(const float* __restrict__ feats,
        float* __restrict__ S1, short* __restrict__ CmF, float* __restrict__ out) {
    int gid = blockIdx.x * 256 + threadIdx.x;    // 0..262143
    if (gid < 2 * NROW) S1[gid] = 0.0f;                       // S1 | S2
    else if (gid < 2 * NROW + 32) ((int*)(S1 + 4 * NROW))[gid - 2 * NROW] = 0;  // cnt
    else if (gid == 2 * NROW + 32) out[0] = 0.0f;
    pack_unit(feats, CmF, gid);
}

// ---- per-pair finalize: 64 unew + 128 loss rows on one wave ---------------
__device__ __forceinline__ void finalize_pair(int b, int lane,
        float* S1, float* S2, float* Praw, float* Draw,
        const int* __restrict__ index, const float* __restrict__ u,
        float* __restrict__ out) {
    __threadfence();                 // acquire side for all lanes
    int rlo = (b << 6) + lane;       // band b row, also the batch element
    int rhi = rlo + BSZ;             // band b+32 row
    float S1lo = __hip_atomic_load(&S1[rlo], __ATOMIC_RELAXED, __HIP_MEMORY_SCOPE_AGENT);
    float S2lo = __hip_atomic_load(&S2[rlo], __ATOMIC_RELAXED, __HIP_MEMORY_SCOPE_AGENT);
    float Plo  = __hip_atomic_load(&Praw[rlo], __ATOMIC_RELAXED, __HIP_MEMORY_SCOPE_AGENT);
    float Dlo  = __hip_atomic_load(&Draw[rlo], __ATOMIC_RELAXED, __HIP_MEMORY_SCOPE_AGENT);
    float S1hi = __hip_atomic_load(&S1[rhi], __ATOMIC_RELAXED, __HIP_MEMORY_SCOPE_AGENT);
    float S2hi = __hip_atomic_load(&S2[rhi], __ATOMIC_RELAXED, __HIP_MEMORY_SCOPE_AGENT);
    float Phi  = __hip_atomic_load(&Praw[rhi], __ATOMIC_RELAXED, __HIP_MEMORY_SCOPE_AGENT);
    float Dhi  = __hip_atomic_load(&Draw[rhi], __ATOMIC_RELAXED, __HIP_MEMORY_SCOPE_AGENT);

    float mlo = -Dlo, mhi = -Dhi;
    float tplo = Plo + mlo, tphi = Phi + mhi;
    float Elo = __builtin_exp2f(mlo) * S1lo;
    float unew = 0.1f * u[index[rlo]] + 0.9f * (Elo - __builtin_exp2f(tplo));

    float Wlo = __builtin_exp2f(mlo) * __builtin_fmaf(mlo, S1lo, S2lo);
    float Whi = __builtin_exp2f(mhi) * __builtin_fmaf(mhi, S1hi, S2hi);
    float etplo = __builtin_exp2f(tplo);
    float etphi = __builtin_exp2f(tphi);
    float local = (tplo - (Wlo - etplo * tplo) / unew)
                + (tphi - (Whi - etphi * tphi) / unew);
    #pragma unroll
    for (int off = 32; off; off >>= 1) local += __shfl_xor(local, off, 64);
    if (lane == 0) atomicAdd(out, -LN2 * local / (float)NROW);
}

// ---------------- barrier-free symmetric GEMM + stats + fused tail ---------
// One 64-thread block == one wave == one 32-row x 64-col half-tile.
__global__ __launch_bounds__(64, 4) void gemm_sym(const short* __restrict__ CmF,
        float* __restrict__ S1, float* __restrict__ S2,
        float* __restrict__ Praw, float* __restrict__ Draw,
        int* __restrict__ cnt, const int* __restrict__ index,
        const float* __restrict__ u, float* __restrict__ out) {
    int lane = threadIdx.x;          // 0..63
    int quad = lane >> 4;
    int l15  = lane & 15;

    int bh = blockIdx.x;
    int h  = bh & 1;                 // half: rows rt in {2h, 2h+1}
    int t  = bh >> 1;
    // triangle decode t -> (p,q), p>=q
    int p = (int)((sqrtf(8.0f * (float)t + 1.0f) - 1.0f) * 0.5f);
    while ((p + 1) * (p + 2) / 2 <= t) ++p;
    while (p * (p + 1) / 2 > t) --p;
    int q = t - p * (p + 1) / 2;
    int rowBase = q << 6;            // row band (64)
    int colBase = p << 6;            // col band, >= row band
    bool offdiag = (p != q);

    int laneOff = ((l15 << 2) + quad) * 8;
    const short* aB = CmF + q * 16384 + laneOff + (h * 2) * 512;  // our 2 rt frags
    const short* bB = CmF + p * 16384 + laneOff;

    f32x4 acc[2][4];
    #pragma unroll
    for (int a = 0; a < 2; ++a)
        #pragma unroll
        for (int c = 0; c < 4; ++c) acc[a][c] = (f32x4){0.f, 0.f, 0.f, 0.f};

    // depth-1 software pipeline: 2 rotating fragment buffers
    bf16x8 aF[2][2], bF[2][4];
    #pragma unroll
    for (int j = 0; j < 2; ++j) aF[0][j] = *(const bf16x8*)(aB + j * 512);
    #pragma unroll
    for (int ct = 0; ct < 4; ++ct) bF[0][ct] = *(const bf16x8*)(bB + ct * 512);

    #pragma unroll
    for (int k = 0; k < 8; ++k) {
        int cur = k & 1;
        int nxt = cur ^ 1;
        if (k < 7) {                 // issue loads for step k+1
            #pragma unroll
            for (int j = 0; j < 2; ++j)
                aF[nxt][j] = *(const bf16x8*)(aB + (k + 1) * 2048 + j * 512);
            #pragma unroll
            for (int ct = 0; ct < 4; ++ct)
                bF[nxt][ct] = *(const bf16x8*)(bB + (k + 1) * 2048 + ct * 512);
        }
        __builtin_amdgcn_s_setprio(1);
        #pragma unroll
        for (int j = 0; j < 2; ++j)
            #pragma unroll
            for (int ct = 0; ct < 4; ++ct)
                acc[j][ct] = __builtin_amdgcn_mfma_f32_16x16x32_bf16(
                    aF[cur][j], bF[cur][ct], acc[j][ct], 0, 0, 0);
        __builtin_amdgcn_s_setprio(0);
    }

    // ---- epilogue: C/D layout col = lane&15, row = quad*4 + reg  [m89/m91]
    float S1r[2][4] = {}, S2r[2][4] = {};
    float S1c[4] = {}, S2c[4] = {};
    #pragma unroll
    for (int j = 0; j < 2; ++j) {
        #pragma unroll
        for (int ct = 0; ct < 4; ++ct) {
            #pragma unroll
            for (int r = 0; r < 4; ++r) {
                float d  = acc[j][ct][r];
                float t0 = d * C1;
                float f  = __builtin_exp2f(t0);
                S1r[j][r] += f;
                S2r[j][r] = __builtin_fmaf(f, t0, S2r[j][r]);
                if (offdiag) {
                    S1c[ct] += f;
                    S2c[ct] = __builtin_fmaf(f, t0, S2c[ct]);
                }
            }
        }
    }

    // ---- Praw: only tiles with p == q^32 contain positives (j = i^2048)
    if (p == (q ^ 32) && quad == (l15 >> 2)) {
        int r = l15 & 3;
        #pragma unroll
        for (int j = 0; j < 2; ++j) {
            int rt = 2 * h + j;
            float t0 = acc[j][rt][r] * C1;     // positive sits at ct == rt
            Praw[rowBase + rt * 16 + l15] = t0;
            Praw[colBase + rt * 16 + l15] = t0;
        }
    }
    // ---- Draw: diagonal tiles hold the self-dot (msd = -Draw in finalize)
    if (!offdiag && quad == (l15 >> 2)) {
        int r = l15 & 3;
        #pragma unroll
        for (int j = 0; j < 2; ++j) {
            int rt = 2 * h + j;
            Draw[rowBase + rt * 16 + l15] = acc[j][rt][r] * C1;
        }
    }

    // row-path: reduce over 16 l15 lanes per row, 1-lane atomic per row
    #pragma unroll
    for (int j = 0; j < 2; ++j) {
        #pragma unroll
        for (int r = 0; r < 4; ++r) {
            float e = S1r[j][r], w = S2r[j][r];
            #pragma unroll
            for (int off = 1; off < 16; off <<= 1) {
                e += __shfl_xor(e, off, 64);
                w += __shfl_xor(w, off, 64);
            }
            if (l15 == 0) {
                int grow = rowBase + (2 * h + j) * 16 + (quad << 2) + r;
                atomicAdd(&S1[grow], e);
                atomicAdd(&S2[grow], w);
            }
        }
    }
    // col-path: reduce over 4 quads per col, 16-lane atomic
    if (offdiag) {
        #pragma unroll
        for (int ct = 0; ct < 4; ++ct) {
            float e = S1c[ct], w = S2c[ct];
            e += __shfl_xor(e, 16, 64);  w += __shfl_xor(w, 16, 64);
            e += __shfl_xor(e, 32, 64);  w += __shfl_xor(w, 32, 64);
            if (quad == 0) {
                int gcol = colBase + ct * 16 + l15;
                atomicAdd(&S1[gcol], e);
                atomicAdd(&S2[gcol], w);
            }
        }
    }

    // ---- completion counters -> fused finalize (atomic causality only) ----
    __threadfence();                 // release: S1/S2 atomics + Praw/Draw stores
    int fp0 = -1, fp1 = -1;
    if (lane == 0) {
        int prA = q & 31, prB = p & 31;
        int o = __hip_atomic_fetch_add(&cnt[prA], 1, __ATOMIC_ACQ_REL,
                                       __HIP_MEMORY_SCOPE_AGENT);
        if (o == PAIR_TGT - 1) fp0 = prA;
        if (prB != prA) {
            o = __hip_atomic_fetch_add(&cnt[prB], 1, __ATOMIC_ACQ_REL,
                                       __HIP_MEMORY_SCOPE_AGENT);
            if (o == PAIR_TGT - 1) fp1 = prB;
        }
    }
    fp0 = __shfl(fp0, 0, 64);
    fp1 = __shfl(fp1, 0, 64);
    if (fp0 >= 0) finalize_pair(fp0, lane, S1, S2, Praw, Draw, index, u, out);
    if (fp1 >= 0) finalize_pair(fp1, lane, S1, S2, Praw, Draw, index, u, out);
}

extern "C" void kernel_launch(void* const* d_in, const int* in_sizes, int n_in,
                              void* d_out, int out_size, void* d_ws, size_t ws_size,
                              hipStream_t stream) {
    const int*   index = (const int*)d_in[0];
    const float* feats = (const float*)d_in[1];
    const float* u     = (const float*)d_in[2];
    float* out = (float*)d_out;

    // ws: [S1|S2|Praw|Draw] (4x4096 f32) | cnt (32 int) | ... | CmF @128KB (2 MB)
    float* S1   = (float*)d_ws;
    float* S2   = S1 + NROW;
    float* Praw = S2 + NROW;
    float* Draw = Praw + NROW;
    int*   cnt  = (int*)(S1 + 4 * NROW);
    short* CmF  = (short*)((char*)d_ws + 131072);

    prep_kernel<<<1024, 256, 0, stream>>>(feats, S1, CmF, out);
    gemm_sym<<<NBLK, 64, 0, stream>>>(CmF, S1, S2, Praw, Draw, cnt, index, u, out);
}

// Round 4
// 111.171 us; speedup vs baseline: 5.7062x; 3.8504x over previous
//
#include <hip/hip_runtime.h>

// BatchIndependentLoss: SupCon-style loss, B=2048, V=2, D=256, N=4096.
// loss = -mean_i( lp_i - (W_i - e^{lp}*lp) / u_new[i%B] )
// R12: revert R11's fence disaster (per-block agent-scope __threadfence =
// buffer_wbl2+inv per block -> L2 thrash, 340us). Back to the R9 dispatch
// train; window decomposition from R10/R11: ~90us is harness-fixed (256MiB
// fill + 60MB u-restore + graph gaps), our kernels+boundaries ~24us.
// Changes vs R9:
//  (a) gemm: depth-2 prefetch restored (R8's 3-buffer pipeline) on full
//      64x64 tiles + R9's single-exp epilogue. At the grid-imposed
//      ~2 waves/SIMD, depth-1 left ~120cy/step of L2 latency exposed;
//      depth-2 covers it within-wave. launch_bounds(64,2), VGPR ~185.
//  (b) finalize parallelized: 32 blocks x 64 (one wave per band-pair
//      {b*64..+63, +2048}), plain loads (kernel boundary = coherence),
//      atomicAdd into out (zeroed in prep). Was 1 block on 1 CU.
// Math identical to R9 (unshifted exp2 domain: f=exp2(d*C1), S1+=f,
// S2+=f*d*C1; per-row 2^msd shift in finalize; msd from diagonal tiles;
// self-term and positive-term inclusion matches reference's neg_mask
// which keeps the diagonal).
//
// CmF layout: shorts, index = ((band*8 + k)*4 + rt)*512 + (l15*4+quad)*8 + j
// Fragment load for (band, k, rt): wave reads one contiguous 1 KB chunk.

#define BSZ   2048
#define NROW  4096
#define NB64  64                       // 4096/64 bands
#define NT2   (NB64 * (NB64 + 1) / 2)  // 2080 upper-triangle 64x64 tiles
#define C1    (1.4426950408889634f / 0.07f)   // log2(e)/TEMPERATURE
#define LN2   0.6931471805599453f

typedef __attribute__((ext_vector_type(8))) __bf16 bf16x8;
typedef __attribute__((ext_vector_type(4))) float f32x4;

__device__ __forceinline__ short f2bs(float x) {
    __bf16 b = (__bf16)x;
    return __builtin_bit_cast(short, b);
}

// contrast row i = v*B + b  ->  features row b*V + v  (fp32, 256 elems)
__device__ __forceinline__ const float* crow_ptr(const float* feats, int i) {
    return feats + (((i & (BSZ - 1)) * 2 + (i >> 11)) << 8);
}

// ---- pack one gid unit (8 shorts) of the frag-major bf16 operand ----------
__device__ __forceinline__ void pack_unit(const float* __restrict__ feats,
                                          short* __restrict__ CmF, int gid) {
    int quad = gid & 3;
    int l15  = (gid >> 2) & 15;
    int rt   = (gid >> 6) & 3;
    int k    = (gid >> 8) & 7;
    int b    = gid >> 12;
    int srow = (b << 6) + (rt << 4) + l15;
    int kel  = (k << 5) + (quad << 3);
    const float4* fp = (const float4*)(crow_ptr(feats, srow) + kel);
    float4 v0 = fp[0], v1 = fp[1];
    short h[8] = { f2bs(v0.x), f2bs(v0.y), f2bs(v0.z), f2bs(v0.w),
                   f2bs(v1.x), f2bs(v1.y), f2bs(v1.z), f2bs(v1.w) };
    *(int4*)(CmF + gid * 8) = *(int4*)h;
}

// ---------------- prep: pack + zero S1/S2/out ------------------------------
__global__ __launch_bounds__(256) void prep_kernel(const float* __restrict__ feats,
        float* __restrict__ S1, short* __restrict__ CmF, float* __restrict__ out) {
    int gid = blockIdx.x * 256 + threadIdx.x;    // 0..262143
    if (gid < 2 * NROW) S1[gid] = 0.0f;          // S1 | S2 contiguous
    else if (gid == 2 * NROW) out[0] = 0.0f;
    pack_unit(feats, CmF, gid);
}

// ---------------- barrier-free symmetric GEMM + stats ----------------------
// One 64-thread block == one wave == one 64x64 upper-tri tile.
// Depth-2 prefetch (3 rotating buffers). Unshifted exp2 domain.
__global__ __launch_bounds__(64, 2) void gemm_sym(const short* __restrict__ CmF,
        float* __restrict__ S1, float* __restrict__ S2,
        float* __restrict__ Praw, float* __restrict__ Draw) {
    int lane = threadIdx.x;          // 0..63
    int quad = lane >> 4;
    int l15  = lane & 15;

    // triangle decode t -> (p,q), p>=q
    int t = blockIdx.x;
    int p = (int)((sqrtf(8.0f * (float)t + 1.0f) - 1.0f) * 0.5f);
    while ((p + 1) * (p + 2) / 2 <= t) ++p;
    while (p * (p + 1) / 2 > t) --p;
    int q = t - p * (p + 1) / 2;
    int rowBase = q << 6;            // row band (64)
    int colBase = p << 6;            // col band, >= row band
    bool offdiag = (p != q);

    int laneOff = ((l15 << 2) + quad) * 8;
    const short* aB = CmF + q * 16384 + laneOff;
    const short* bB = CmF + p * 16384 + laneOff;

    f32x4 acc[4][4];
    #pragma unroll
    for (int a = 0; a < 4; ++a)
        #pragma unroll
        for (int c = 0; c < 4; ++c) acc[a][c] = (f32x4){0.f, 0.f, 0.f, 0.f};

    // depth-2 software pipeline: 3 rotating fragment buffers
    bf16x8 aF[3][4], bF[3][4];
    #pragma unroll
    for (int rt = 0; rt < 4; ++rt) {
        aF[0][rt] = *(const bf16x8*)(aB + (0 * 4 + rt) * 512);
        bF[0][rt] = *(const bf16x8*)(bB + (0 * 4 + rt) * 512);
    }
    #pragma unroll
    for (int rt = 0; rt < 4; ++rt) {
        aF[1][rt] = *(const bf16x8*)(aB + (1 * 4 + rt) * 512);
        bF[1][rt] = *(const bf16x8*)(bB + (1 * 4 + rt) * 512);
    }

    #pragma unroll
    for (int k = 0; k < 8; ++k) {
        int cur = k % 3;
        int nxt = (k + 2) % 3;
        if (k < 6) {                 // issue loads for step k+2 (2 ahead)
            #pragma unroll
            for (int rt = 0; rt < 4; ++rt) {
                aF[nxt][rt] = *(const bf16x8*)(aB + ((k + 2) * 4 + rt) * 512);
                bF[nxt][rt] = *(const bf16x8*)(bB + ((k + 2) * 4 + rt) * 512);
            }
        }
        __builtin_amdgcn_s_setprio(1);
        #pragma unroll
        for (int rt = 0; rt < 4; ++rt)
            #pragma unroll
            for (int ct = 0; ct < 4; ++ct)
                acc[rt][ct] = __builtin_amdgcn_mfma_f32_16x16x32_bf16(
                    aF[cur][rt], bF[cur][ct], acc[rt][ct], 0, 0, 0);
        __builtin_amdgcn_s_setprio(0);
    }

    // ---- epilogue: C/D layout col = lane&15, row = quad*4 + reg  [m89/m91]
    // Unshifted domain: one exp2 per element, feeds BOTH row and col sums.
    float S1r[4][4] = {}, S2r[4][4] = {};
    float S1c[4] = {}, S2c[4] = {};
    #pragma unroll
    for (int rt = 0; rt < 4; ++rt) {
        #pragma unroll
        for (int ct = 0; ct < 4; ++ct) {
            #pragma unroll
            for (int r = 0; r < 4; ++r) {
                float d  = acc[rt][ct][r];
                float t0 = d * C1;
                float f  = __builtin_exp2f(t0);
                S1r[rt][r] += f;
                S2r[rt][r] = __builtin_fmaf(f, t0, S2r[rt][r]);
                if (offdiag) {
                    S1c[ct] += f;
                    S2c[ct] = __builtin_fmaf(f, t0, S2c[ct]);
                }
            }
        }
    }

    // ---- Praw: only tiles with p == q^32 contain positives (j = i^2048)
    if (p == (q ^ 32) && quad == (l15 >> 2)) {
        int r = l15 & 3;
        #pragma unroll
        for (int rt = 0; rt < 4; ++rt) {
            float t0 = acc[rt][rt][r] * C1;    // positive sits at ct == rt
            Praw[rowBase + rt * 16 + l15] = t0;
            Praw[colBase + rt * 16 + l15] = t0;
        }
    }
    // ---- Draw: diagonal tiles hold the self-dot (msd = -Draw in finalize)
    if (!offdiag && quad == (l15 >> 2)) {
        int r = l15 & 3;
        #pragma unroll
        for (int rt = 0; rt < 4; ++rt)
            Draw[rowBase + rt * 16 + l15] = acc[rt][rt][r] * C1;
    }

    // row-path: reduce over 16 l15 lanes per row, 1-lane atomic per row
    #pragma unroll
    for (int rt = 0; rt < 4; ++rt) {
        #pragma unroll
        for (int r = 0; r < 4; ++r) {
            float e = S1r[rt][r], w = S2r[rt][r];
            #pragma unroll
            for (int off = 1; off < 16; off <<= 1) {
                e += __shfl_xor(e, off, 64);
                w += __shfl_xor(w, off, 64);
            }
            if (l15 == 0) {
                int grow = rowBase + rt * 16 + (quad << 2) + r;
                atomicAdd(&S1[grow], e);
                atomicAdd(&S2[grow], w);
            }
        }
    }
    // col-path: reduce over 4 quads per col, 16-lane atomic
    if (offdiag) {
        #pragma unroll
        for (int ct = 0; ct < 4; ++ct) {
            float e = S1c[ct], w = S2c[ct];
            e += __shfl_xor(e, 16, 64);  w += __shfl_xor(w, 16, 64);
            e += __shfl_xor(e, 32, 64);  w += __shfl_xor(w, 32, 64);
            if (quad == 0) {
                int gcol = colBase + ct * 16 + l15;
                atomicAdd(&S1[gcol], e);
                atomicAdd(&S2[gcol], w);
            }
        }
    }
}

// ---------------- finalize: 32 blocks x 64, one wave per band-pair ---------
// block b owns rows rlo = b*64+lane (batch elems, view 0) and rhi = rlo+2048
// (view 1). unew is per-lane (same batch elem for both rows). m = -Draw;
// E = 2^m*S1; W = 2^m*(S2 + m*S1); tp = Praw + m.
__global__ __launch_bounds__(64) void finalize_kernel(const int* __restrict__ index,
        const float* __restrict__ u, const float* __restrict__ S1,
        const float* __restrict__ S2, const float* __restrict__ Praw,
        const float* __restrict__ Draw, float* __restrict__ out) {
    int lane = threadIdx.x;
    int rlo  = (blockIdx.x << 6) + lane;   // 0..2047
    int rhi  = rlo + BSZ;                  // 2048..4095

    float mlo = -Draw[rlo], mhi = -Draw[rhi];
    float tplo = Praw[rlo] + mlo, tphi = Praw[rhi] + mhi;
    float Elo  = __builtin_exp2f(mlo) * S1[rlo];
    float unew = 0.1f * u[index[rlo]] + 0.9f * (Elo - __builtin_exp2f(tplo));

    float Wlo = __builtin_exp2f(mlo) * __builtin_fmaf(mlo, S1[rlo], S2[rlo]);
    float Whi = __builtin_exp2f(mhi) * __builtin_fmaf(mhi, S1[rhi], S2[rhi]);
    float etplo = __builtin_exp2f(tplo);
    float etphi = __builtin_exp2f(tphi);
    float local = (tplo - (Wlo - etplo * tplo) / unew)
                + (tphi - (Whi - etphi * tphi) / unew);
    #pragma unroll
    for (int off = 32; off; off >>= 1) local += __shfl_xor(local, off, 64);
    if (lane == 0) atomicAdd(out, -LN2 * local / (float)NROW);
}

extern "C" void kernel_launch(void* const* d_in, const int* in_sizes, int n_in,
                              void* d_out, int out_size, void* d_ws, size_t ws_size,
                              hipStream_t stream) {
    const int*   index = (const int*)d_in[0];
    const float* feats = (const float*)d_in[1];
    const float* u     = (const float*)d_in[2];
    float* out = (float*)d_out;

    // ws: [S1|S2|Praw|Draw] (4x4096 f32 = 64 KB) | ... | CmF @128KB (2 MB)
    float* S1   = (float*)d_ws;
    float* S2   = S1 + NROW;
    float* Praw = S2 + NROW;
    float* Draw = Praw + NROW;
    short* CmF  = (short*)((char*)d_ws + 131072);

    prep_kernel<<<1024, 256, 0, stream>>>(feats, S1, CmF, out);
    gemm_sym<<<NT2, 64, 0, stream>>>(CmF, S1, S2, Praw, Draw);
    finalize_kernel<<<32, 64, 0, stream>>>(index, u, S1, S2, Praw, Draw, out);
}